// Round 20
// baseline (417.593 us; speedup 1.0000x reference)
//
#include <hip/hip_runtime.h>
#include <hip/hip_bf16.h>
#include <stdint.h>

typedef __hip_bfloat16 bf16;
typedef short short4v __attribute__((ext_vector_type(4)));
typedef short short8 __attribute__((ext_vector_type(8)));
typedef float f32x4 __attribute__((ext_vector_type(4)));
typedef float f32x16 __attribute__((ext_vector_type(16)));

#define NB 128
#define NPIX 196      // 14*14
#define NPAD 208      // 13*16
#define VP 208        // v4 row pitch (13*16 for PV K=16 steps), cols [196,208) zero
#define QROWS 208     // q/k rows allocated+written (pad rows zeroed)
#define NH 8
#define KD 32
#define DHEAD 128
#define DH 1024
#define DIM 384
#define SCALE 0.17677669529663687f

__device__ __forceinline__ float b2f(bf16 v) { return __bfloat162float(v); }
__device__ __forceinline__ bf16 f2b(float f) { return __float2bfloat16(f); }
__device__ __forceinline__ float us2f(unsigned short u) {
  union { unsigned int i; float f; } v; v.i = (unsigned int)u << 16; return v.f;
}
__device__ __forceinline__ short f2us(float f) {
  bf16 b = __float2bfloat16(f);
  return *(short*)&b;
}

// CK-style global->LDS 16B async copy
__device__ __forceinline__ void gll16(const void* g, void* l) {
  auto gp = reinterpret_cast<const uint32_t __attribute__((address_space(1)))*>(
      reinterpret_cast<uintptr_t>(g));
  auto lp = reinterpret_cast<uint32_t __attribute__((address_space(3)))*>(
      reinterpret_cast<uintptr_t>(l));
  __builtin_amdgcn_global_load_lds(gp, lp, 16, 0, 0);
}

// ---------- fp32 -> bf16 weight conversion + ab2/c1 table precompute ----------
__global__ __launch_bounds__(256) void k_cvt4(const float* __restrict__ s0,
                                              const float* __restrict__ s1,
                                              const float* __restrict__ s2,
                                              const float* __restrict__ s3,
                                              bf16* __restrict__ dst,
                                              const float* __restrict__ th1w,
                                              const float* __restrict__ th1b,
                                              const float* __restrict__ ab,
                                              float* __restrict__ ab2g,
                                              float* __restrict__ c1g) {
  if (blockIdx.x >= 3840) {
    int t = threadIdx.x;
    for (int pos = t; pos < NH * NPIX; pos += 256) {
      int g = pos / NPIX, off = pos - g * NPIX;
      float s = th1b[g];
#pragma unroll
      for (int h = 0; h < 8; ++h)
        s += th1w[g * 8 + h] * ab[h * NPIX + off];
      ab2g[pos] = s;
    }
    if (t < 64) c1g[t] = th1w[t] * SCALE;
    return;
  }
  int i = blockIdx.x * 256 + threadIdx.x;  // < 983040 exactly
  const float* src; int o;
  if (i < 98304)       { src = s0; o = i; }
  else if (i < 196608) { src = s1; o = i - 98304; }
  else if (i < 589824) { src = s2; o = i - 196608; }
  else                 { src = s3; o = i - 589824; }
  dst[i] = f2b(src[o]);
}

// ---------- transpose x (B,384,196) fp32 -> XT (B,208,384) bf16, rows >=196 zeroed ----------
__global__ __launch_bounds__(256) void k_xt(const float* __restrict__ x,
                                            bf16* __restrict__ XT) {
  __shared__ bf16 tile[32][33];
  int ct = blockIdx.x, nt = blockIdx.y, b = blockIdx.z;
  int c0 = ct * 32, n0 = nt * 32;
  int tc = threadIdx.x >> 5, tn = threadIdx.x & 31;
#pragma unroll
  for (int r = 0; r < 4; ++r) {
    int c = tc + r * 8;
    int n = n0 + tn;
    float v = 0.f;
    if (n < NPIX) v = x[((size_t)b * DIM + c0 + c) * NPIX + n];
    tile[c][tn] = f2b(v);
  }
  __syncthreads();
#pragma unroll
  for (int r = 0; r < 4; ++r) {
    int n = n0 + tc + r * 8;
    if (n < NPAD) XT[((size_t)b * NPAD + n) * DIM + c0 + tn] = tile[tn][tc + r * 8];
  }
}

// ---------- fused QKV projection: LDS-staged 128x128 tile GEMM ----------
__global__ __launch_bounds__(256, 2) void k_qkv2(
    const bf16* __restrict__ Wf, const bf16* __restrict__ XT,
    const float* __restrict__ qb, const float* __restrict__ qs, const float* __restrict__ qt,
    const float* __restrict__ kb, const float* __restrict__ ks, const float* __restrict__ kt,
    const float* __restrict__ vb, const float* __restrict__ vs, const float* __restrict__ vt,
    bf16* __restrict__ qf, bf16* __restrict__ kf, bf16* __restrict__ v4) {
  __shared__ __align__(16) char lds[2][32768];  // [buf][A 16KB | B 16KB]
  const int NWG = 12 * 208;  // 2496, %8==0
  int id = blockIdx.x;
  int id2 = (id & 7) * (NWG >> 3) + (id >> 3);  // XCD-contiguous
  int mt = id2 % 12, nt = id2 / 12;
  int m0 = mt * 128, n0 = nt * 128;
  int tid = threadIdx.x, lane = tid & 63;
  int wv = tid >> 6, wm = wv >> 1, wn = wv & 1;

  f32x4 acc[4][4];
#pragma unroll
  for (int mi = 0; mi < 4; ++mi)
#pragma unroll
    for (int ni = 0; ni < 4; ++ni)
#pragma unroll
      for (int r = 0; r < 4; ++r) acc[mi][ni][r] = 0.f;

  auto stage = [&](int buf, int t) {
    int k0 = t * 64;
#pragma unroll
    for (int j = 0; j < 4; ++j) {
      int gi = tid + j * 256;
      int row = gi >> 3, g = gi & 7;
      int sk = k0 + ((g ^ (row & 7)) << 3);
      gll16(Wf + (size_t)(m0 + row) * DIM + sk, &lds[buf][gi * 16]);
      gll16(XT + (size_t)(n0 + row) * DIM + sk, &lds[buf][16384 + gi * 16]);
    }
  };
  auto compute = [&](int buf) {
    const char* Ab = lds[buf];
    const char* Bb = lds[buf] + 16384;
    int kq = lane >> 4, il = lane & 15;
#pragma unroll
    for (int ksb = 0; ksb < 2; ++ksb) {
      int G = ksb * 4 + kq;
      short8 af[4], bfr[4];
#pragma unroll
      for (int mi = 0; mi < 4; ++mi) {
        int row = wm * 64 + mi * 16 + il;
        af[mi] = *(const short8*)(Ab + row * 128 + ((G ^ (row & 7)) << 4));
      }
#pragma unroll
      for (int ni = 0; ni < 4; ++ni) {
        int row = wn * 64 + ni * 16 + il;
        bfr[ni] = *(const short8*)(Bb + row * 128 + ((G ^ (row & 7)) << 4));
      }
#pragma unroll
      for (int mi = 0; mi < 4; ++mi)
#pragma unroll
        for (int ni = 0; ni < 4; ++ni)
          acc[mi][ni] = __builtin_amdgcn_mfma_f32_16x16x32_bf16(af[mi], bfr[ni], acc[mi][ni], 0, 0, 0);
    }
  };

  stage(0, 0);
  __syncthreads();
  for (int t = 0; t < 6; ++t) {
    if (t < 5) stage((t + 1) & 1, t + 1);
    compute(t & 1);
    __syncthreads();
  }

  int cq = lane >> 4, cn = lane & 15;
#pragma unroll
  for (int mi = 0; mi < 4; ++mi) {
    int mbase = m0 + wm * 64 + mi * 16;
    const float *bp, *sp, *tp;
    int segbase, segid;
    if (mbase < 256)      { bp = qb; sp = qs; tp = qt; segbase = 0;   segid = 0; }
    else if (mbase < 512) { bp = kb; sp = ks; tp = kt; segbase = 256; segid = 1; }
    else                  { bp = vb; sp = vs; tp = vt; segbase = 512; segid = 2; }
#pragma unroll
    for (int r = 0; r < 4; ++r) {
      int ms = mbase - segbase + cq * 4 + r;
      float bi = bp[ms], sc = sp[ms], tt = tp[ms];
#pragma unroll
      for (int ni = 0; ni < 4; ++ni) {
        int n = n0 + wn * 64 + ni * 16 + cn;
        int b = n / NPAD;
        int nn = n - b * NPAD;
        float y = (acc[mi][ni][r] + bi) * sc + tt;
        y = (nn < NPIX) ? y : 0.f;
        if (segid == 2) {
          v4[((size_t)b * DH + ms) * VP + nn] = f2b(y);
        } else {
          bf16* dst = segid ? kf : qf;
          dst[(((size_t)b * NH + (ms >> 5)) * QROWS + nn) * KD + (ms & 31)] = f2b(y);
        }
      }
    }
  }
}

// ---------- final projection: LDS-staged 128x128 tile GEMM, fp32 out ----------
__global__ __launch_bounds__(256, 2) void k_p2(
    const bf16* __restrict__ Pw, const bf16* __restrict__ OT,
    const float* __restrict__ pb, const float* __restrict__ ps, const float* __restrict__ pt,
    float* __restrict__ out) {
  __shared__ __align__(16) char lds[2][32768];
  const int NWG = 3 * 208;  // 624, %8==0
  int id = blockIdx.x;
  int id2 = (id & 7) * (NWG >> 3) + (id >> 3);
  int mt = id2 % 3, nt = id2 / 3;
  int m0 = mt * 128, n0 = nt * 128;
  int tid = threadIdx.x, lane = tid & 63;
  int wv = tid >> 6, wm = wv >> 1, wn = wv & 1;

  f32x4 acc[4][4];
#pragma unroll
  for (int mi = 0; mi < 4; ++mi)
#pragma unroll
    for (int ni = 0; ni < 4; ++ni)
#pragma unroll
      for (int r = 0; r < 4; ++r) acc[mi][ni][r] = 0.f;

  auto stage = [&](int buf, int t) {
    int k0 = t * 64;
#pragma unroll
    for (int j = 0; j < 4; ++j) {
      int gi = tid + j * 256;
      int row = gi >> 3, g = gi & 7;
      int sk = k0 + ((g ^ (row & 7)) << 3);
      gll16(Pw + (size_t)(m0 + row) * DH + sk, &lds[buf][gi * 16]);
      gll16(OT + (size_t)(n0 + row) * DH + sk, &lds[buf][16384 + gi * 16]);
    }
  };
  auto compute = [&](int buf) {
    const char* Ab = lds[buf];
    const char* Bb = lds[buf] + 16384;
    int kq = lane >> 4, il = lane & 15;
#pragma unroll
    for (int ksb = 0; ksb < 2; ++ksb) {
      int G = ksb * 4 + kq;
      short8 af[4], bfr[4];
#pragma unroll
      for (int mi = 0; mi < 4; ++mi) {
        int row = wm * 64 + mi * 16 + il;
        af[mi] = *(const short8*)(Ab + row * 128 + ((G ^ (row & 7)) << 4));
      }
#pragma unroll
      for (int ni = 0; ni < 4; ++ni) {
        int row = wn * 64 + ni * 16 + il;
        bfr[ni] = *(const short8*)(Bb + row * 128 + ((G ^ (row & 7)) << 4));
      }
#pragma unroll
      for (int mi = 0; mi < 4; ++mi)
#pragma unroll
        for (int ni = 0; ni < 4; ++ni)
          acc[mi][ni] = __builtin_amdgcn_mfma_f32_16x16x32_bf16(af[mi], bfr[ni], acc[mi][ni], 0, 0, 0);
    }
  };

  stage(0, 0);
  __syncthreads();
  for (int t = 0; t < 16; ++t) {
    if (t < 15) stage((t + 1) & 1, t + 1);
    compute(t & 1);
    __syncthreads();
  }

  int cq = lane >> 4, cn = lane & 15;
#pragma unroll
  for (int mi = 0; mi < 4; ++mi) {
#pragma unroll
    for (int r = 0; r < 4; ++r) {
      int m = m0 + wm * 64 + mi * 16 + cq * 4 + r;
      float bi = pb[m], sc = ps[m], tt = pt[m];
#pragma unroll
      for (int ni = 0; ni < 4; ++ni) {
        int n = n0 + wn * 64 + ni * 16 + cn;
        int b = n / NPAD;
        int nn = n - b * NPAD;
        if (nn < NPIX)
          out[((size_t)b * DIM + m) * NPIX + nn] = (acc[mi][ni][r] + bi) * sc + tt;
      }
    }
  }
}

// ---------- depthwise 3x3 + BN, fused with per-channel column sums ----------
__global__ __launch_bounds__(256) void k_dwv(
    const bf16* __restrict__ v4, const float* __restrict__ lvw,
    const float* __restrict__ lvb, const float* __restrict__ lvs,
    const float* __restrict__ lvt, bf16* __restrict__ vl,
    float* __restrict__ vcs) {
  int blk = blockIdx.x;
  int b = blk >> 8, cg = blk & 255;
  int lc = threadIdx.x >> 6, px = threadIdx.x & 63;
  int ch = cg * 4 + lc;
  const bf16* src = v4 + ((size_t)b * DH + ch) * VP;
  float w[9];
#pragma unroll
  for (int i = 0; i < 9; ++i) w[i] = lvw[ch * 9 + i];
  float bb = lvb[ch], ss = lvs[ch], tt = lvt[ch];
  bf16* dst = vl + ((size_t)b * DH + ch) * NPIX;
  float csum = 0.f;
  for (int p = px; p < NPIX; p += 64) {
    int ri = p / 14, ci = p - ri * 14;
    float s = 0.f;
#pragma unroll
    for (int dy = -1; dy <= 1; ++dy)
#pragma unroll
      for (int dx = -1; dx <= 1; ++dx) {
        int rr = ri + dy, cc = ci + dx;
        if (rr >= 0 && rr < 14 && cc >= 0 && cc < 14)
          s += w[(dy + 1) * 3 + dx + 1] * b2f(src[rr * 14 + cc]);
      }
    csum += b2f(src[p]);
    dst[p] = f2b((s + bb) * ss + tt);
  }
  csum += __shfl_xor(csum, 1);
  csum += __shfl_xor(csum, 2);
  csum += __shfl_xor(csum, 4);
  csum += __shfl_xor(csum, 8);
  csum += __shfl_xor(csum, 16);
  csum += __shfl_xor(csum, 32);
  if (px == 0) vcs[b * DH + ch] = csum;
}

// ---------- attention ----------
// S: bf16 [8 heads][16 rows][224-col pitch, 208 used], rotate-swizzled.
// SROW=448 -> LDS 57856 B -> exactly 2 blocks/CU (L2-friendly regime; R8/R12-verified).
// Softmax: no max-sub (logits ~|6| << 88); exp folded into pass A's register
// epilogue -> the softmax phase is a read-only sum sweep.
#define SROW 448  // bytes per S row
__device__ __forceinline__ int saddr(int g, int i, int j) {
  int r = j * 2 + ((i & 7) << 4);
  if (r >= SROW) r -= SROW;
  return (g * 16 + i) * SROW + r;
}

__global__ __launch_bounds__(512, 4) void k_att(
    const bf16* __restrict__ qf, const bf16* __restrict__ kf,
    const bf16* __restrict__ v4, const bf16* __restrict__ vl,
    const float* __restrict__ vcs,
    const float* __restrict__ ab2g, const float* __restrict__ c1g,
    const float* __restrict__ th2w, const float* __restrict__ th2b,
    bf16* __restrict__ OT) {
  __shared__ __align__(16) char smem[NH * 16 * SROW];  // 57344 B
  __shared__ float smInv[NH * 16];                     // 512 B
  // batch->XCD affinity: all 13 Q-tiles of a batch share one XCD's L2.
  int id = blockIdx.x;            // 1664 linear
  int xcd = id & 7;
  int rest = id >> 3;             // [0,208)
  int qt = rest % 13;
  int b = (rest / 13) * 8 + xcd;  // [0,128), b%8 == xcd
  int i0 = qt * 16;
  int tid = threadIdx.x;
  int wave = tid >> 6, lane = tid & 63;
  int il = lane & 15, kh = lane >> 4;

  // ---- QK^T, head = wave; 16 q-rows x 208 k-rows, raw qk -> S (bf16) ----
  {
    const bf16* qp = qf + ((size_t)b * NH + wave) * QROWS * KD;
    const bf16* kp = kf + ((size_t)b * NH + wave) * QROWS * KD;
    short8 a = *(const short8*)(qp + (i0 + il) * KD + kh * 8);
    for (int jt = 0; jt < 13; ++jt) {
      short8 bb = *(const short8*)(kp + (jt * 16 + il) * KD + kh * 8);
      f32x4 acc = {0.f, 0.f, 0.f, 0.f};
      acc = __builtin_amdgcn_mfma_f32_16x16x32_bf16(a, bb, acc, 0, 0, 0);
      int j = jt * 16 + il;
#pragma unroll
      for (int r = 0; r < 4; ++r)
        *(bf16*)(smem + saddr(wave, kh * 4 + r, j)) = f2b(acc[r]);
    }
  }
  __syncthreads();
  // ---- pass A: th1-mix + bias, writes exp(S') directly (from fp32 registers) ----
  for (int pos = tid; pos < 16 * NPIX; pos += 512) {
    int i = pos / NPIX, j = pos - i * NPIX;
    float sv[8];
#pragma unroll
    for (int h = 0; h < 8; ++h) sv[h] = b2f(*(const bf16*)(smem + saddr(h, i, j)));
    int ia = i0 + i; if (ia > 195) ia = 195;
    int ri = ia / 14, ci = ia - ri * 14;
    int rj = j / 14, cj = j - rj * 14;
    int dr = ri > rj ? ri - rj : rj - ri;
    int dc = ci > cj ? ci - cj : cj - ci;
    int off = dr * 14 + dc;
    float outv[8];
#pragma unroll
    for (int g = 0; g < 8; ++g) {
      float s = ab2g[g * NPIX + off];
#pragma unroll
      for (int h = 0; h < 8; ++h) s += c1g[g * 8 + h] * sv[h];
      outv[g] = s;
    }
#pragma unroll
    for (int g = 0; g < 8; ++g)
      *(bf16*)(smem + saddr(g, i, j)) = f2b(__expf(outv[g]));
  }
  __syncthreads();
  // ---- softmax denom: READ-ONLY sum sweep (exp already in S); 1/sum -> smInv ----
  {
    int row = tid >> 2, part = tid & 3;  // 128 rows = 8 heads x 16
    int g = row >> 4, i = row & 15;
    int jb = part * 52;
    int n4 = (part == 3) ? 10 : 13;  // part 3 covers j in [156,196)
    float s = 0.f;
    for (int it = 0; it < n4; ++it) {
      short4v v = *(const short4v*)(smem + saddr(g, i, jb + it * 4));
#pragma unroll
      for (int t = 0; t < 4; ++t) s += us2f((unsigned short)v[t]);
    }
    if (part == 3) {  // zero pad cols [196,208)
      short4v z = {0, 0, 0, 0};
#pragma unroll
      for (int it = 0; it < 3; ++it)
        *(short4v*)(smem + saddr(g, i, 196 + it * 4)) = z;
    }
    s += __shfl_xor(s, 1);
    s += __shfl_xor(s, 2);
    if (part == 0) smInv[row] = 1.f / s;
  }
  __syncthreads();
  // ---- pass C: talking-head-2 mix with folded 1/sum ----
  for (int pos = tid; pos < 16 * NPIX; pos += 512) {
    int i = pos / NPIX, j = pos - i * NPIX;
    float pv[8];
#pragma unroll
    for (int g = 0; g < 8; ++g)
      pv[g] = b2f(*(const bf16*)(smem + saddr(g, i, j))) * smInv[g * 16 + i];
#pragma unroll
    for (int g2 = 0; g2 < 8; ++g2) {
      float s = 0.f;
#pragma unroll
      for (int g = 0; g < 8; ++g) s += th2w[g2 * 8 + g] * pv[g];
      *(bf16*)(smem + saddr(g2, i, j)) = f2b(s);
    }
  }
  __syncthreads();
  // ---- PV via mfma_f32_32x32x16_bf16, A=P (rows=i), B=V (cols=ch) ----
  // D[m=i (rows 0..15 valid)][n=ch-sub (32 lanes)] -> coalesced 64B OT stores.
  {
    int g = wave;
    int cl = lane & 31, s = lane >> 5;
    const bf16* vb0 = v4 + ((size_t)b * DH + g * DHEAD) * VP;
    float t2b = th2b[g];
#pragma unroll
    for (int dt2 = 0; dt2 < 4; ++dt2) {
      f32x16 acc;
#pragma unroll
      for (int r = 0; r < 16; ++r) acc[r] = 0.f;
      const bf16* vrow = vb0 + (size_t)(dt2 * 32 + cl) * VP + s * 8;
      for (int ks = 0; ks < 13; ++ks) {
        short8 pa = *(const short8*)(smem + saddr(g, cl & 15, ks * 16 + s * 8));
        short8 av = *(const short8*)(vrow + ks * 16);
        acc = __builtin_amdgcn_mfma_f32_32x32x16_bf16(pa, av, acc, 0, 0, 0);
      }
      int ch = g * DHEAD + dt2 * 32 + cl;
      float csv = vcs[b * DH + ch] * t2b;
      const bf16* vlrow = vl + ((size_t)b * DH + ch) * NPIX;
      bf16* otcol = OT + (size_t)b * NPAD * DH + ch;
#pragma unroll
      for (int reg = 0; reg < 8; ++reg) {  // D rows 0..15 only
        int i = (reg & 3) + 8 * (reg >> 2) + 4 * s;
        int n = i0 + i;
        if (n < NPIX) {
          float val = acc[reg] + csv + b2f(vlrow[n]);
          otcol[(size_t)n * DH] = f2b(fmaxf(val, 0.f));
        } else {
          otcol[(size_t)n * DH] = f2b(0.f);
        }
      }
    }
  }
}

extern "C" void kernel_launch(void* const* d_in, const int* in_sizes, int n_in,
                              void* d_out, int out_size, void* d_ws, size_t ws_size,
                              hipStream_t stream) {
  const float* x    = (const float*)d_in[0];
  const float* qw   = (const float*)d_in[1];
  const float* qb   = (const float*)d_in[2];
  const float* q_s  = (const float*)d_in[3];
  const float* q_t  = (const float*)d_in[4];
  const float* kw   = (const float*)d_in[5];
  const float* kb   = (const float*)d_in[6];
  const float* k_s  = (const float*)d_in[7];
  const float* k_t  = (const float*)d_in[8];
  const float* vw   = (const float*)d_in[9];
  const float* vb   = (const float*)d_in[10];
  const float* v_s  = (const float*)d_in[11];
  const float* v_t  = (const float*)d_in[12];
  const float* lvw  = (const float*)d_in[13];
  const float* lvb  = (const float*)d_in[14];
  const float* lv_s = (const float*)d_in[15];
  const float* lv_t = (const float*)d_in[16];
  const float* th1w = (const float*)d_in[17];
  const float* th1b = (const float*)d_in[18];
  const float* th2w = (const float*)d_in[19];
  const float* th2b = (const float*)d_in[20];
  const float* ab   = (const float*)d_in[21];
  const float* pw   = (const float*)d_in[22];
  const float* pb   = (const float*)d_in[23];
  const float* p_s  = (const float*)d_in[24];
  const float* p_t  = (const float*)d_in[25];

  char* ws = (char*)d_ws;
  size_t off = 0;
  auto alloc = [&](size_t bytes) {
    char* p = ws + off;
    off += (bytes + 255) & ~(size_t)255;
    return p;
  };
  // region0: XT (B,208,384 bf16) aliased with OT (B,208,1024 bf16)
  char* region0 = alloc((size_t)NB * NPAD * DH * 2);
  bf16* XT  = (bf16*)region0;
  bf16* OT  = (bf16*)region0;
  bf16* qfb = (bf16*)alloc((size_t)NB * NH * QROWS * KD * 2);
  bf16* kfb = (bf16*)alloc((size_t)NB * NH * QROWS * KD * 2);
  bf16* v4  = (bf16*)alloc((size_t)NB * DH * VP * 2);
  bf16* vlb = (bf16*)alloc((size_t)NB * DH * NPIX * 2);
  float* vcs = (float*)alloc((size_t)NB * DH * 4);
  bf16* wf  = (bf16*)alloc((size_t)1536 * DIM * 2);  // fused Q|K|V weights
  bf16* wpb = (bf16*)alloc((size_t)DIM * DH * 2);    // immediately follows wf
  float* ab2g = (float*)alloc((size_t)NH * NPIX * 4);
  float* c1g  = (float*)alloc((size_t)64 * 4);
  (void)ws_size; (void)in_sizes; (void)n_in; (void)out_size;

  k_cvt4<<<dim3(3841), 256, 0, stream>>>(qw, kw, vw, pw, wf, th1w, th1b, ab,
                                         ab2g, c1g);
  k_xt<<<dim3(12, 7, NB), 256, 0, stream>>>(x, XT);
  k_qkv2<<<dim3(2496), 256, 0, stream>>>(wf, XT, qb, q_s, q_t, kb, k_s, k_t,
                                         vb, v_s, v_t, qfb, kfb, v4);
  k_dwv<<<dim3(NB * 256), 256, 0, stream>>>(v4, lvw, lvb, lv_s, lv_t, vlb, vcs);
  k_att<<<dim3(1664), 512, 0, stream>>>(qfb, kfb, v4, vlb, vcs,
                                        ab2g, c1g, th2w, th2b, OT);
  k_p2<<<dim3(624), 256, 0, stream>>>(wpb, OT, pb, p_s, p_t, (float*)d_out);
}

// Round 21
// 416.725 us; speedup vs baseline: 1.0021x; 1.0021x over previous
//
#include <hip/hip_runtime.h>
#include <hip/hip_bf16.h>
#include <stdint.h>

typedef __hip_bfloat16 bf16;
typedef short short4v __attribute__((ext_vector_type(4)));
typedef short short8 __attribute__((ext_vector_type(8)));
typedef float f32x4 __attribute__((ext_vector_type(4)));
typedef float f32x16 __attribute__((ext_vector_type(16)));

#define NB 128
#define NPIX 196      // 14*14
#define NPAD 208      // 13*16
#define VP 208        // v4 row pitch (13*16 for PV K=16 steps), cols [196,208) zero
#define QROWS 208     // q/k rows allocated+written (pad rows zeroed)
#define NH 8
#define KD 32
#define DHEAD 128
#define DH 1024
#define DIM 384
#define SCALE 0.17677669529663687f

__device__ __forceinline__ float b2f(bf16 v) { return __bfloat162float(v); }
__device__ __forceinline__ bf16 f2b(float f) { return __float2bfloat16(f); }
__device__ __forceinline__ float us2f(unsigned short u) {
  union { unsigned int i; float f; } v; v.i = (unsigned int)u << 16; return v.f;
}
__device__ __forceinline__ short f2us(float f) {
  bf16 b = __float2bfloat16(f);
  return *(short*)&b;
}

// CK-style global->LDS 16B async copy
__device__ __forceinline__ void gll16(const void* g, void* l) {
  auto gp = reinterpret_cast<const uint32_t __attribute__((address_space(1)))*>(
      reinterpret_cast<uintptr_t>(g));
  auto lp = reinterpret_cast<uint32_t __attribute__((address_space(3)))*>(
      reinterpret_cast<uintptr_t>(l));
  __builtin_amdgcn_global_load_lds(gp, lp, 16, 0, 0);
}

// ---------- fp32 -> bf16 weight conversion + ab2/c1 table precompute ----------
__global__ __launch_bounds__(256) void k_cvt4(const float* __restrict__ s0,
                                              const float* __restrict__ s1,
                                              const float* __restrict__ s2,
                                              const float* __restrict__ s3,
                                              bf16* __restrict__ dst,
                                              const float* __restrict__ th1w,
                                              const float* __restrict__ th1b,
                                              const float* __restrict__ ab,
                                              float* __restrict__ ab2g,
                                              float* __restrict__ c1g) {
  if (blockIdx.x >= 3840) {
    int t = threadIdx.x;
    for (int pos = t; pos < NH * NPIX; pos += 256) {
      int g = pos / NPIX, off = pos - g * NPIX;
      float s = th1b[g];
#pragma unroll
      for (int h = 0; h < 8; ++h)
        s += th1w[g * 8 + h] * ab[h * NPIX + off];
      ab2g[pos] = s;
    }
    if (t < 64) c1g[t] = th1w[t] * SCALE;
    return;
  }
  int i = blockIdx.x * 256 + threadIdx.x;  // < 983040 exactly
  const float* src; int o;
  if (i < 98304)       { src = s0; o = i; }
  else if (i < 196608) { src = s1; o = i - 98304; }
  else if (i < 589824) { src = s2; o = i - 196608; }
  else                 { src = s3; o = i - 589824; }
  dst[i] = f2b(src[o]);
}

// ---------- transpose x (B,384,196) fp32 -> XT (B,208,384) bf16, rows >=196 zeroed ----------
__global__ __launch_bounds__(256) void k_xt(const float* __restrict__ x,
                                            bf16* __restrict__ XT) {
  __shared__ bf16 tile[32][33];
  int ct = blockIdx.x, nt = blockIdx.y, b = blockIdx.z;
  int c0 = ct * 32, n0 = nt * 32;
  int tc = threadIdx.x >> 5, tn = threadIdx.x & 31;
#pragma unroll
  for (int r = 0; r < 4; ++r) {
    int c = tc + r * 8;
    int n = n0 + tn;
    float v = 0.f;
    if (n < NPIX) v = x[((size_t)b * DIM + c0 + c) * NPIX + n];
    tile[c][tn] = f2b(v);
  }
  __syncthreads();
#pragma unroll
  for (int r = 0; r < 4; ++r) {
    int n = n0 + tc + r * 8;
    if (n < NPAD) XT[((size_t)b * NPAD + n) * DIM + c0 + tn] = tile[tn][tc + r * 8];
  }
}

// ---------- fused QKV projection: LDS-staged 128x128 tile GEMM ----------
__global__ __launch_bounds__(256, 2) void k_qkv2(
    const bf16* __restrict__ Wf, const bf16* __restrict__ XT,
    const float* __restrict__ qb, const float* __restrict__ qs, const float* __restrict__ qt,
    const float* __restrict__ kb, const float* __restrict__ ks, const float* __restrict__ kt,
    const float* __restrict__ vb, const float* __restrict__ vs, const float* __restrict__ vt,
    bf16* __restrict__ qf, bf16* __restrict__ kf, bf16* __restrict__ v4) {
  __shared__ __align__(16) char lds[2][32768];  // [buf][A 16KB | B 16KB]
  const int NWG = 12 * 208;  // 2496, %8==0
  int id = blockIdx.x;
  int id2 = (id & 7) * (NWG >> 3) + (id >> 3);  // XCD-contiguous
  int mt = id2 % 12, nt = id2 / 12;
  int m0 = mt * 128, n0 = nt * 128;
  int tid = threadIdx.x, lane = tid & 63;
  int wv = tid >> 6, wm = wv >> 1, wn = wv & 1;

  f32x4 acc[4][4];
#pragma unroll
  for (int mi = 0; mi < 4; ++mi)
#pragma unroll
    for (int ni = 0; ni < 4; ++ni)
#pragma unroll
      for (int r = 0; r < 4; ++r) acc[mi][ni][r] = 0.f;

  auto stage = [&](int buf, int t) {
    int k0 = t * 64;
#pragma unroll
    for (int j = 0; j < 4; ++j) {
      int gi = tid + j * 256;
      int row = gi >> 3, g = gi & 7;
      int sk = k0 + ((g ^ (row & 7)) << 3);
      gll16(Wf + (size_t)(m0 + row) * DIM + sk, &lds[buf][gi * 16]);
      gll16(XT + (size_t)(n0 + row) * DIM + sk, &lds[buf][16384 + gi * 16]);
    }
  };
  auto compute = [&](int buf) {
    const char* Ab = lds[buf];
    const char* Bb = lds[buf] + 16384;
    int kq = lane >> 4, il = lane & 15;
#pragma unroll
    for (int ksb = 0; ksb < 2; ++ksb) {
      int G = ksb * 4 + kq;
      short8 af[4], bfr[4];
#pragma unroll
      for (int mi = 0; mi < 4; ++mi) {
        int row = wm * 64 + mi * 16 + il;
        af[mi] = *(const short8*)(Ab + row * 128 + ((G ^ (row & 7)) << 4));
      }
#pragma unroll
      for (int ni = 0; ni < 4; ++ni) {
        int row = wn * 64 + ni * 16 + il;
        bfr[ni] = *(const short8*)(Bb + row * 128 + ((G ^ (row & 7)) << 4));
      }
#pragma unroll
      for (int mi = 0; mi < 4; ++mi)
#pragma unroll
        for (int ni = 0; ni < 4; ++ni)
          acc[mi][ni] = __builtin_amdgcn_mfma_f32_16x16x32_bf16(af[mi], bfr[ni], acc[mi][ni], 0, 0, 0);
    }
  };

  stage(0, 0);
  __syncthreads();
  for (int t = 0; t < 6; ++t) {
    if (t < 5) stage((t + 1) & 1, t + 1);
    compute(t & 1);
    __syncthreads();
  }

  int cq = lane >> 4, cn = lane & 15;
#pragma unroll
  for (int mi = 0; mi < 4; ++mi) {
    int mbase = m0 + wm * 64 + mi * 16;
    const float *bp, *sp, *tp;
    int segbase, segid;
    if (mbase < 256)      { bp = qb; sp = qs; tp = qt; segbase = 0;   segid = 0; }
    else if (mbase < 512) { bp = kb; sp = ks; tp = kt; segbase = 256; segid = 1; }
    else                  { bp = vb; sp = vs; tp = vt; segbase = 512; segid = 2; }
#pragma unroll
    for (int r = 0; r < 4; ++r) {
      int ms = mbase - segbase + cq * 4 + r;
      float bi = bp[ms], sc = sp[ms], tt = tp[ms];
#pragma unroll
      for (int ni = 0; ni < 4; ++ni) {
        int n = n0 + wn * 64 + ni * 16 + cn;
        int b = n / NPAD;
        int nn = n - b * NPAD;
        float y = (acc[mi][ni][r] + bi) * sc + tt;
        y = (nn < NPIX) ? y : 0.f;
        if (segid == 2) {
          v4[((size_t)b * DH + ms) * VP + nn] = f2b(y);
        } else {
          bf16* dst = segid ? kf : qf;
          dst[(((size_t)b * NH + (ms >> 5)) * QROWS + nn) * KD + (ms & 31)] = f2b(y);
        }
      }
    }
  }
}

// ---------- final projection: LDS-staged 128x128 tile GEMM, fp32 out ----------
__global__ __launch_bounds__(256, 2) void k_p2(
    const bf16* __restrict__ Pw, const bf16* __restrict__ OT,
    const float* __restrict__ pb, const float* __restrict__ ps, const float* __restrict__ pt,
    float* __restrict__ out) {
  __shared__ __align__(16) char lds[2][32768];
  const int NWG = 3 * 208;  // 624, %8==0
  int id = blockIdx.x;
  int id2 = (id & 7) * (NWG >> 3) + (id >> 3);
  int mt = id2 % 3, nt = id2 / 3;
  int m0 = mt * 128, n0 = nt * 128;
  int tid = threadIdx.x, lane = tid & 63;
  int wv = tid >> 6, wm = wv >> 1, wn = wv & 1;

  f32x4 acc[4][4];
#pragma unroll
  for (int mi = 0; mi < 4; ++mi)
#pragma unroll
    for (int ni = 0; ni < 4; ++ni)
#pragma unroll
      for (int r = 0; r < 4; ++r) acc[mi][ni][r] = 0.f;

  auto stage = [&](int buf, int t) {
    int k0 = t * 64;
#pragma unroll
    for (int j = 0; j < 4; ++j) {
      int gi = tid + j * 256;
      int row = gi >> 3, g = gi & 7;
      int sk = k0 + ((g ^ (row & 7)) << 3);
      gll16(Pw + (size_t)(m0 + row) * DH + sk, &lds[buf][gi * 16]);
      gll16(OT + (size_t)(n0 + row) * DH + sk, &lds[buf][16384 + gi * 16]);
    }
  };
  auto compute = [&](int buf) {
    const char* Ab = lds[buf];
    const char* Bb = lds[buf] + 16384;
    int kq = lane >> 4, il = lane & 15;
#pragma unroll
    for (int ksb = 0; ksb < 2; ++ksb) {
      int G = ksb * 4 + kq;
      short8 af[4], bfr[4];
#pragma unroll
      for (int mi = 0; mi < 4; ++mi) {
        int row = wm * 64 + mi * 16 + il;
        af[mi] = *(const short8*)(Ab + row * 128 + ((G ^ (row & 7)) << 4));
      }
#pragma unroll
      for (int ni = 0; ni < 4; ++ni) {
        int row = wn * 64 + ni * 16 + il;
        bfr[ni] = *(const short8*)(Bb + row * 128 + ((G ^ (row & 7)) << 4));
      }
#pragma unroll
      for (int mi = 0; mi < 4; ++mi)
#pragma unroll
        for (int ni = 0; ni < 4; ++ni)
          acc[mi][ni] = __builtin_amdgcn_mfma_f32_16x16x32_bf16(af[mi], bfr[ni], acc[mi][ni], 0, 0, 0);
    }
  };

  stage(0, 0);
  __syncthreads();
  for (int t = 0; t < 16; ++t) {
    if (t < 15) stage((t + 1) & 1, t + 1);
    compute(t & 1);
    __syncthreads();
  }

  int cq = lane >> 4, cn = lane & 15;
#pragma unroll
  for (int mi = 0; mi < 4; ++mi) {
#pragma unroll
    for (int r = 0; r < 4; ++r) {
      int m = m0 + wm * 64 + mi * 16 + cq * 4 + r;
      float bi = pb[m], sc = ps[m], tt = pt[m];
#pragma unroll
      for (int ni = 0; ni < 4; ++ni) {
        int n = n0 + wn * 64 + ni * 16 + cn;
        int b = n / NPAD;
        int nn = n - b * NPAD;
        if (nn < NPIX)
          out[((size_t)b * DIM + m) * NPIX + nn] = (acc[mi][ni][r] + bi) * sc + tt;
      }
    }
  }
}

// ---------- depthwise 3x3 + BN, fused with per-channel column sums ----------
__global__ __launch_bounds__(256) void k_dwv(
    const bf16* __restrict__ v4, const float* __restrict__ lvw,
    const float* __restrict__ lvb, const float* __restrict__ lvs,
    const float* __restrict__ lvt, bf16* __restrict__ vl,
    float* __restrict__ vcs) {
  int blk = blockIdx.x;
  int b = blk >> 8, cg = blk & 255;
  int lc = threadIdx.x >> 6, px = threadIdx.x & 63;
  int ch = cg * 4 + lc;
  const bf16* src = v4 + ((size_t)b * DH + ch) * VP;
  float w[9];
#pragma unroll
  for (int i = 0; i < 9; ++i) w[i] = lvw[ch * 9 + i];
  float bb = lvb[ch], ss = lvs[ch], tt = lvt[ch];
  bf16* dst = vl + ((size_t)b * DH + ch) * NPIX;
  float csum = 0.f;
  for (int p = px; p < NPIX; p += 64) {
    int ri = p / 14, ci = p - ri * 14;
    float s = 0.f;
#pragma unroll
    for (int dy = -1; dy <= 1; ++dy)
#pragma unroll
      for (int dx = -1; dx <= 1; ++dx) {
        int rr = ri + dy, cc = ci + dx;
        if (rr >= 0 && rr < 14 && cc >= 0 && cc < 14)
          s += w[(dy + 1) * 3 + dx + 1] * b2f(src[rr * 14 + cc]);
      }
    csum += b2f(src[p]);
    dst[p] = f2b((s + bb) * ss + tt);
  }
  csum += __shfl_xor(csum, 1);
  csum += __shfl_xor(csum, 2);
  csum += __shfl_xor(csum, 4);
  csum += __shfl_xor(csum, 8);
  csum += __shfl_xor(csum, 16);
  csum += __shfl_xor(csum, 32);
  if (px == 0) vcs[b * DH + ch] = csum;
}

// ---------- attention ----------
// S: bf16 [8 heads][16 rows][224-col pitch, 208 used], rotate-swizzled.
// SROW=448 -> LDS 57856 B -> exactly 2 blocks/CU (L2-friendly regime; R8/R12-verified).
// Softmax: no max-sub (logits ~|6| << 88); exp folded into pass A's register
// epilogue -> the softmax phase is a read-only sum sweep.
#define SROW 448  // bytes per S row
__device__ __forceinline__ int saddr(int g, int i, int j) {
  int r = j * 2 + ((i & 7) << 4);
  if (r >= SROW) r -= SROW;
  return (g * 16 + i) * SROW + r;
}

__global__ __launch_bounds__(512, 4) void k_att(
    const bf16* __restrict__ qf, const bf16* __restrict__ kf,
    const bf16* __restrict__ v4, const bf16* __restrict__ vl,
    const float* __restrict__ vcs,
    const float* __restrict__ ab2g, const float* __restrict__ c1g,
    const float* __restrict__ th2w, const float* __restrict__ th2b,
    bf16* __restrict__ OT) {
  __shared__ __align__(16) char smem[NH * 16 * SROW];  // 57344 B
  __shared__ float smInv[NH * 16];                     // 512 B
  // batch->XCD affinity: all 13 Q-tiles of a batch share one XCD's L2.
  int id = blockIdx.x;            // 1664 linear
  int xcd = id & 7;
  int rest = id >> 3;             // [0,208)
  int qt = rest % 13;
  int b = (rest / 13) * 8 + xcd;  // [0,128), b%8 == xcd
  int i0 = qt * 16;
  int tid = threadIdx.x;
  int wave = tid >> 6, lane = tid & 63;
  int il = lane & 15, kh = lane >> 4;

  // ---- QK^T, head = wave; 16 q-rows x 208 k-rows, raw qk -> S (bf16) ----
  {
    const bf16* qp = qf + ((size_t)b * NH + wave) * QROWS * KD;
    const bf16* kp = kf + ((size_t)b * NH + wave) * QROWS * KD;
    short8 a = *(const short8*)(qp + (i0 + il) * KD + kh * 8);
    for (int jt = 0; jt < 13; ++jt) {
      short8 bb = *(const short8*)(kp + (jt * 16 + il) * KD + kh * 8);
      f32x4 acc = {0.f, 0.f, 0.f, 0.f};
      acc = __builtin_amdgcn_mfma_f32_16x16x32_bf16(a, bb, acc, 0, 0, 0);
      int j = jt * 16 + il;
#pragma unroll
      for (int r = 0; r < 4; ++r)
        *(bf16*)(smem + saddr(wave, kh * 4 + r, j)) = f2b(acc[r]);
    }
  }
  __syncthreads();
  // ---- pass A: th1-mix + bias, writes exp(S') directly (from fp32 registers) ----
  for (int pos = tid; pos < 16 * NPIX; pos += 512) {
    int i = pos / NPIX, j = pos - i * NPIX;
    float sv[8];
#pragma unroll
    for (int h = 0; h < 8; ++h) sv[h] = b2f(*(const bf16*)(smem + saddr(h, i, j)));
    int ia = i0 + i; if (ia > 195) ia = 195;
    int ri = ia / 14, ci = ia - ri * 14;
    int rj = j / 14, cj = j - rj * 14;
    int dr = ri > rj ? ri - rj : rj - ri;
    int dc = ci > cj ? ci - cj : cj - ci;
    int off = dr * 14 + dc;
    float outv[8];
#pragma unroll
    for (int g = 0; g < 8; ++g) {
      float s = ab2g[g * NPIX + off];
#pragma unroll
      for (int h = 0; h < 8; ++h) s += c1g[g * 8 + h] * sv[h];
      outv[g] = s;
    }
#pragma unroll
    for (int g = 0; g < 8; ++g)
      *(bf16*)(smem + saddr(g, i, j)) = f2b(__expf(outv[g]));
  }
  __syncthreads();
  // ---- softmax denom: READ-ONLY sum sweep (exp already in S); 1/sum -> smInv ----
  {
    int row = tid >> 2, part = tid & 3;  // 128 rows = 8 heads x 16
    int g = row >> 4, i = row & 15;
    int jb = part * 52;
    int n4 = (part == 3) ? 10 : 13;  // part 3 covers j in [156,196)
    float s = 0.f;
    for (int it = 0; it < n4; ++it) {
      short4v v = *(const short4v*)(smem + saddr(g, i, jb + it * 4));
#pragma unroll
      for (int t = 0; t < 4; ++t) s += us2f((unsigned short)v[t]);
    }
    if (part == 3) {  // zero pad cols [196,208)
      short4v z = {0, 0, 0, 0};
#pragma unroll
      for (int it = 0; it < 3; ++it)
        *(short4v*)(smem + saddr(g, i, 196 + it * 4)) = z;
    }
    s += __shfl_xor(s, 1);
    s += __shfl_xor(s, 2);
    if (part == 0) smInv[row] = 1.f / s;
  }
  __syncthreads();
  // ---- pass C: talking-head-2 mix with folded 1/sum ----
  for (int pos = tid; pos < 16 * NPIX; pos += 512) {
    int i = pos / NPIX, j = pos - i * NPIX;
    float pv[8];
#pragma unroll
    for (int g = 0; g < 8; ++g)
      pv[g] = b2f(*(const bf16*)(smem + saddr(g, i, j))) * smInv[g * 16 + i];
#pragma unroll
    for (int g2 = 0; g2 < 8; ++g2) {
      float s = 0.f;
#pragma unroll
      for (int g = 0; g < 8; ++g) s += th2w[g2 * 8 + g] * pv[g];
      *(bf16*)(smem + saddr(g2, i, j)) = f2b(s);
    }
  }
  __syncthreads();
  // ---- PV via mfma_f32_32x32x16_bf16, A=P (rows=i), B=V (cols=ch) ----
  // D[m=i (rows 0..15 valid)][n=ch-sub (32 lanes)] -> coalesced 64B OT stores.
  {
    int g = wave;
    int cl = lane & 31, s = lane >> 5;
    const bf16* vb0 = v4 + ((size_t)b * DH + g * DHEAD) * VP;
    float t2b = th2b[g];
#pragma unroll
    for (int dt2 = 0; dt2 < 4; ++dt2) {
      f32x16 acc;
#pragma unroll
      for (int r = 0; r < 16; ++r) acc[r] = 0.f;
      const bf16* vrow = vb0 + (size_t)(dt2 * 32 + cl) * VP + s * 8;
      for (int ks = 0; ks < 13; ++ks) {
        short8 pa = *(const short8*)(smem + saddr(g, cl & 15, ks * 16 + s * 8));
        short8 av = *(const short8*)(vrow + ks * 16);
        acc = __builtin_amdgcn_mfma_f32_32x32x16_bf16(pa, av, acc, 0, 0, 0);
      }
      int ch = g * DHEAD + dt2 * 32 + cl;
      float csv = vcs[b * DH + ch] * t2b;
      const bf16* vlrow = vl + ((size_t)b * DH + ch) * NPIX;
      bf16* otcol = OT + (size_t)b * NPAD * DH + ch;
#pragma unroll
      for (int reg = 0; reg < 8; ++reg) {  // D rows 0..15 only
        int i = (reg & 3) + 8 * (reg >> 2) + 4 * s;
        int n = i0 + i;
        if (n < NPIX) {
          float val = acc[reg] + csv + b2f(vlrow[n]);
          otcol[(size_t)n * DH] = f2b(fmaxf(val, 0.f));
        } else {
          otcol[(size_t)n * DH] = f2b(0.f);
        }
      }
    }
  }
}

extern "C" void kernel_launch(void* const* d_in, const int* in_sizes, int n_in,
                              void* d_out, int out_size, void* d_ws, size_t ws_size,
                              hipStream_t stream) {
  const float* x    = (const float*)d_in[0];
  const float* qw   = (const float*)d_in[1];
  const float* qb   = (const float*)d_in[2];
  const float* q_s  = (const float*)d_in[3];
  const float* q_t  = (const float*)d_in[4];
  const float* kw   = (const float*)d_in[5];
  const float* kb   = (const float*)d_in[6];
  const float* k_s  = (const float*)d_in[7];
  const float* k_t  = (const float*)d_in[8];
  const float* vw   = (const float*)d_in[9];
  const float* vb   = (const float*)d_in[10];
  const float* v_s  = (const float*)d_in[11];
  const float* v_t  = (const float*)d_in[12];
  const float* lvw  = (const float*)d_in[13];
  const float* lvb  = (const float*)d_in[14];
  const float* lv_s = (const float*)d_in[15];
  const float* lv_t = (const float*)d_in[16];
  const float* th1w = (const float*)d_in[17];
  const float* th1b = (const float*)d_in[18];
  const float* th2w = (const float*)d_in[19];
  const float* th2b = (const float*)d_in[20];
  const float* ab   = (const float*)d_in[21];
  const float* pw   = (const float*)d_in[22];
  const float* pb   = (const float*)d_in[23];
  const float* p_s  = (const float*)d_in[24];
  const float* p_t  = (const float*)d_in[25];

  char* ws = (char*)d_ws;
  size_t off = 0;
  auto alloc = [&](size_t bytes) {
    char* p = ws + off;
    off += (bytes + 255) & ~(size_t)255;
    return p;
  };
  // region0: XT (B,208,384 bf16) aliased with OT (B,208,1024 bf16)
  char* region0 = alloc((size_t)NB * NPAD * DH * 2);
  bf16* XT  = (bf16*)region0;
  bf16* OT  = (bf16*)region0;
  bf16* qfb = (bf16*)alloc((size_t)NB * NH * QROWS * KD * 2);
  bf16* kfb = (bf16*)alloc((size_t)NB * NH * QROWS * KD * 2);
  bf16* v4  = (bf16*)alloc((size_t)NB * DH * VP * 2);
  bf16* vlb = (bf16*)alloc((size_t)NB * DH * NPIX * 2);
  float* vcs = (float*)alloc((size_t)NB * DH * 4);
  bf16* wf  = (bf16*)alloc((size_t)1536 * DIM * 2);  // fused Q|K|V weights
  bf16* wpb = (bf16*)alloc((size_t)DIM * DH * 2);    // immediately follows wf
  float* ab2g = (float*)alloc((size_t)NH * NPIX * 4);
  float* c1g  = (float*)alloc((size_t)64 * 4);
  (void)ws_size; (void)in_sizes; (void)n_in; (void)out_size;

  k_cvt4<<<dim3(3841), 256, 0, stream>>>(qw, kw, vw, pw, wf, th1w, th1b, ab,
                                         ab2g, c1g);
  k_xt<<<dim3(12, 7, NB), 256, 0, stream>>>(x, XT);
  k_qkv2<<<dim3(2496), 256, 0, stream>>>(wf, XT, qb, q_s, q_t, kb, k_s, k_t,
                                         vb, v_s, v_t, qfb, kfb, v4);
  k_dwv<<<dim3(NB * 256), 256, 0, stream>>>(v4, lvw, lvb, lv_s, lv_t, vlb, vcs);
  k_att<<<dim3(1664), 512, 0, stream>>>(qfb, kfb, v4, vlb, vcs,
                                        ab2g, c1g, th2w, th2b, OT);
  k_p2<<<dim3(624), 256, 0, stream>>>(wpb, OT, pb, p_s, p_t, (float*)d_out);
}

// Round 22
// 415.968 us; speedup vs baseline: 1.0039x; 1.0018x over previous
//
#include <hip/hip_runtime.h>
#include <hip/hip_bf16.h>
#include <stdint.h>

typedef __hip_bfloat16 bf16;
typedef short short4v __attribute__((ext_vector_type(4)));
typedef short short8 __attribute__((ext_vector_type(8)));
typedef float f32x4 __attribute__((ext_vector_type(4)));
typedef float f32x16 __attribute__((ext_vector_type(16)));

#define NB 128
#define NPIX 196      // 14*14
#define NPAD 208      // 13*16
#define VP 208        // v4 row pitch (13*16 for PV K=16 steps), cols [196,208) zero
#define QROWS 208     // q/k rows allocated+written (pad rows zeroed)
#define NH 8
#define KD 32
#define DHEAD 128
#define DH 1024
#define DIM 384
#define SCALE 0.17677669529663687f

__device__ __forceinline__ float b2f(bf16 v) { return __bfloat162float(v); }
__device__ __forceinline__ bf16 f2b(float f) { return __float2bfloat16(f); }
__device__ __forceinline__ float us2f(unsigned short u) {
  union { unsigned int i; float f; } v; v.i = (unsigned int)u << 16; return v.f;
}
__device__ __forceinline__ short f2us(float f) {
  bf16 b = __float2bfloat16(f);
  return *(short*)&b;
}

// CK-style global->LDS 16B async copy
__device__ __forceinline__ void gll16(const void* g, void* l) {
  auto gp = reinterpret_cast<const uint32_t __attribute__((address_space(1)))*>(
      reinterpret_cast<uintptr_t>(g));
  auto lp = reinterpret_cast<uint32_t __attribute__((address_space(3)))*>(
      reinterpret_cast<uintptr_t>(l));
  __builtin_amdgcn_global_load_lds(gp, lp, 16, 0, 0);
}

// ---------- fp32 -> bf16 weight conversion + ab2/c1 table precompute ----------
__global__ __launch_bounds__(256) void k_cvt4(const float* __restrict__ s0,
                                              const float* __restrict__ s1,
                                              const float* __restrict__ s2,
                                              const float* __restrict__ s3,
                                              bf16* __restrict__ dst,
                                              const float* __restrict__ th1w,
                                              const float* __restrict__ th1b,
                                              const float* __restrict__ ab,
                                              float* __restrict__ ab2g,
                                              float* __restrict__ c1g) {
  if (blockIdx.x >= 3840) {
    int t = threadIdx.x;
    for (int pos = t; pos < NH * NPIX; pos += 256) {
      int g = pos / NPIX, off = pos - g * NPIX;
      float s = th1b[g];
#pragma unroll
      for (int h = 0; h < 8; ++h)
        s += th1w[g * 8 + h] * ab[h * NPIX + off];
      ab2g[pos] = s;
    }
    if (t < 64) c1g[t] = th1w[t] * SCALE;
    return;
  }
  int i = blockIdx.x * 256 + threadIdx.x;  // < 983040 exactly
  const float* src; int o;
  if (i < 98304)       { src = s0; o = i; }
  else if (i < 196608) { src = s1; o = i - 98304; }
  else if (i < 589824) { src = s2; o = i - 196608; }
  else                 { src = s3; o = i - 589824; }
  dst[i] = f2b(src[o]);
}

// ---------- transpose x (B,384,196) fp32 -> XT (B,208,384) bf16, rows >=196 zeroed ----------
__global__ __launch_bounds__(256) void k_xt(const float* __restrict__ x,
                                            bf16* __restrict__ XT) {
  __shared__ bf16 tile[32][33];
  int ct = blockIdx.x, nt = blockIdx.y, b = blockIdx.z;
  int c0 = ct * 32, n0 = nt * 32;
  int tc = threadIdx.x >> 5, tn = threadIdx.x & 31;
#pragma unroll
  for (int r = 0; r < 4; ++r) {
    int c = tc + r * 8;
    int n = n0 + tn;
    float v = 0.f;
    if (n < NPIX) v = x[((size_t)b * DIM + c0 + c) * NPIX + n];
    tile[c][tn] = f2b(v);
  }
  __syncthreads();
#pragma unroll
  for (int r = 0; r < 4; ++r) {
    int n = n0 + tc + r * 8;
    if (n < NPAD) XT[((size_t)b * NPAD + n) * DIM + c0 + tn] = tile[tn][tc + r * 8];
  }
}

// ---------- fused QKV projection: LDS-staged 128x128 tile GEMM ----------
__global__ __launch_bounds__(256, 2) void k_qkv2(
    const bf16* __restrict__ Wf, const bf16* __restrict__ XT,
    const float* __restrict__ qb, const float* __restrict__ qs, const float* __restrict__ qt,
    const float* __restrict__ kb, const float* __restrict__ ks, const float* __restrict__ kt,
    const float* __restrict__ vb, const float* __restrict__ vs, const float* __restrict__ vt,
    bf16* __restrict__ qf, bf16* __restrict__ kf, bf16* __restrict__ v4) {
  __shared__ __align__(16) char lds[2][32768];  // [buf][A 16KB | B 16KB]
  const int NWG = 12 * 208;  // 2496, %8==0
  int id = blockIdx.x;
  int id2 = (id & 7) * (NWG >> 3) + (id >> 3);  // XCD-contiguous
  int mt = id2 % 12, nt = id2 / 12;
  int m0 = mt * 128, n0 = nt * 128;
  int tid = threadIdx.x, lane = tid & 63;
  int wv = tid >> 6, wm = wv >> 1, wn = wv & 1;

  f32x4 acc[4][4];
#pragma unroll
  for (int mi = 0; mi < 4; ++mi)
#pragma unroll
    for (int ni = 0; ni < 4; ++ni)
#pragma unroll
      for (int r = 0; r < 4; ++r) acc[mi][ni][r] = 0.f;

  auto stage = [&](int buf, int t) {
    int k0 = t * 64;
#pragma unroll
    for (int j = 0; j < 4; ++j) {
      int gi = tid + j * 256;
      int row = gi >> 3, g = gi & 7;
      int sk = k0 + ((g ^ (row & 7)) << 3);
      gll16(Wf + (size_t)(m0 + row) * DIM + sk, &lds[buf][gi * 16]);
      gll16(XT + (size_t)(n0 + row) * DIM + sk, &lds[buf][16384 + gi * 16]);
    }
  };
  auto compute = [&](int buf) {
    const char* Ab = lds[buf];
    const char* Bb = lds[buf] + 16384;
    int kq = lane >> 4, il = lane & 15;
#pragma unroll
    for (int ksb = 0; ksb < 2; ++ksb) {
      int G = ksb * 4 + kq;
      short8 af[4], bfr[4];
#pragma unroll
      for (int mi = 0; mi < 4; ++mi) {
        int row = wm * 64 + mi * 16 + il;
        af[mi] = *(const short8*)(Ab + row * 128 + ((G ^ (row & 7)) << 4));
      }
#pragma unroll
      for (int ni = 0; ni < 4; ++ni) {
        int row = wn * 64 + ni * 16 + il;
        bfr[ni] = *(const short8*)(Bb + row * 128 + ((G ^ (row & 7)) << 4));
      }
#pragma unroll
      for (int mi = 0; mi < 4; ++mi)
#pragma unroll
        for (int ni = 0; ni < 4; ++ni)
          acc[mi][ni] = __builtin_amdgcn_mfma_f32_16x16x32_bf16(af[mi], bfr[ni], acc[mi][ni], 0, 0, 0);
    }
  };

  stage(0, 0);
  __syncthreads();
  for (int t = 0; t < 6; ++t) {
    if (t < 5) stage((t + 1) & 1, t + 1);
    compute(t & 1);
    __syncthreads();
  }

  int cq = lane >> 4, cn = lane & 15;
#pragma unroll
  for (int mi = 0; mi < 4; ++mi) {
    int mbase = m0 + wm * 64 + mi * 16;
    const float *bp, *sp, *tp;
    int segbase, segid;
    if (mbase < 256)      { bp = qb; sp = qs; tp = qt; segbase = 0;   segid = 0; }
    else if (mbase < 512) { bp = kb; sp = ks; tp = kt; segbase = 256; segid = 1; }
    else                  { bp = vb; sp = vs; tp = vt; segbase = 512; segid = 2; }
#pragma unroll
    for (int r = 0; r < 4; ++r) {
      int ms = mbase - segbase + cq * 4 + r;
      float bi = bp[ms], sc = sp[ms], tt = tp[ms];
#pragma unroll
      for (int ni = 0; ni < 4; ++ni) {
        int n = n0 + wn * 64 + ni * 16 + cn;
        int b = n / NPAD;
        int nn = n - b * NPAD;
        float y = (acc[mi][ni][r] + bi) * sc + tt;
        y = (nn < NPIX) ? y : 0.f;
        if (segid == 2) {
          v4[((size_t)b * DH + ms) * VP + nn] = f2b(y);
        } else {
          bf16* dst = segid ? kf : qf;
          dst[(((size_t)b * NH + (ms >> 5)) * QROWS + nn) * KD + (ms & 31)] = f2b(y);
        }
      }
    }
  }
}

// ---------- final projection: LDS-staged 128x128 tile GEMM, fp32 out ----------
__global__ __launch_bounds__(256, 2) void k_p2(
    const bf16* __restrict__ Pw, const bf16* __restrict__ OT,
    const float* __restrict__ pb, const float* __restrict__ ps, const float* __restrict__ pt,
    float* __restrict__ out) {
  __shared__ __align__(16) char lds[2][32768];
  const int NWG = 3 * 208;  // 624, %8==0
  int id = blockIdx.x;
  int id2 = (id & 7) * (NWG >> 3) + (id >> 3);
  int mt = id2 % 3, nt = id2 / 3;
  int m0 = mt * 128, n0 = nt * 128;
  int tid = threadIdx.x, lane = tid & 63;
  int wv = tid >> 6, wm = wv >> 1, wn = wv & 1;

  f32x4 acc[4][4];
#pragma unroll
  for (int mi = 0; mi < 4; ++mi)
#pragma unroll
    for (int ni = 0; ni < 4; ++ni)
#pragma unroll
      for (int r = 0; r < 4; ++r) acc[mi][ni][r] = 0.f;

  auto stage = [&](int buf, int t) {
    int k0 = t * 64;
#pragma unroll
    for (int j = 0; j < 4; ++j) {
      int gi = tid + j * 256;
      int row = gi >> 3, g = gi & 7;
      int sk = k0 + ((g ^ (row & 7)) << 3);
      gll16(Pw + (size_t)(m0 + row) * DH + sk, &lds[buf][gi * 16]);
      gll16(OT + (size_t)(n0 + row) * DH + sk, &lds[buf][16384 + gi * 16]);
    }
  };
  auto compute = [&](int buf) {
    const char* Ab = lds[buf];
    const char* Bb = lds[buf] + 16384;
    int kq = lane >> 4, il = lane & 15;
#pragma unroll
    for (int ksb = 0; ksb < 2; ++ksb) {
      int G = ksb * 4 + kq;
      short8 af[4], bfr[4];
#pragma unroll
      for (int mi = 0; mi < 4; ++mi) {
        int row = wm * 64 + mi * 16 + il;
        af[mi] = *(const short8*)(Ab + row * 128 + ((G ^ (row & 7)) << 4));
      }
#pragma unroll
      for (int ni = 0; ni < 4; ++ni) {
        int row = wn * 64 + ni * 16 + il;
        bfr[ni] = *(const short8*)(Bb + row * 128 + ((G ^ (row & 7)) << 4));
      }
#pragma unroll
      for (int mi = 0; mi < 4; ++mi)
#pragma unroll
        for (int ni = 0; ni < 4; ++ni)
          acc[mi][ni] = __builtin_amdgcn_mfma_f32_16x16x32_bf16(af[mi], bfr[ni], acc[mi][ni], 0, 0, 0);
    }
  };

  stage(0, 0);
  __syncthreads();
  for (int t = 0; t < 16; ++t) {
    if (t < 15) stage((t + 1) & 1, t + 1);
    compute(t & 1);
    __syncthreads();
  }

  int cq = lane >> 4, cn = lane & 15;
#pragma unroll
  for (int mi = 0; mi < 4; ++mi) {
#pragma unroll
    for (int r = 0; r < 4; ++r) {
      int m = m0 + wm * 64 + mi * 16 + cq * 4 + r;
      float bi = pb[m], sc = ps[m], tt = pt[m];
#pragma unroll
      for (int ni = 0; ni < 4; ++ni) {
        int n = n0 + wn * 64 + ni * 16 + cn;
        int b = n / NPAD;
        int nn = n - b * NPAD;
        if (nn < NPIX)
          out[((size_t)b * DIM + m) * NPIX + nn] = (acc[mi][ni][r] + bi) * sc + tt;
      }
    }
  }
}

// ---------- depthwise 3x3 + BN, fused with per-channel column sums ----------
__global__ __launch_bounds__(256) void k_dwv(
    const bf16* __restrict__ v4, const float* __restrict__ lvw,
    const float* __restrict__ lvb, const float* __restrict__ lvs,
    const float* __restrict__ lvt, bf16* __restrict__ vl,
    float* __restrict__ vcs) {
  int blk = blockIdx.x;
  int b = blk >> 8, cg = blk & 255;
  int lc = threadIdx.x >> 6, px = threadIdx.x & 63;
  int ch = cg * 4 + lc;
  const bf16* src = v4 + ((size_t)b * DH + ch) * VP;
  float w[9];
#pragma unroll
  for (int i = 0; i < 9; ++i) w[i] = lvw[ch * 9 + i];
  float bb = lvb[ch], ss = lvs[ch], tt = lvt[ch];
  bf16* dst = vl + ((size_t)b * DH + ch) * NPIX;
  float csum = 0.f;
  for (int p = px; p < NPIX; p += 64) {
    int ri = p / 14, ci = p - ri * 14;
    float s = 0.f;
#pragma unroll
    for (int dy = -1; dy <= 1; ++dy)
#pragma unroll
      for (int dx = -1; dx <= 1; ++dx) {
        int rr = ri + dy, cc = ci + dx;
        if (rr >= 0 && rr < 14 && cc >= 0 && cc < 14)
          s += w[(dy + 1) * 3 + dx + 1] * b2f(src[rr * 14 + cc]);
      }
    csum += b2f(src[p]);
    dst[p] = f2b((s + bb) * ss + tt);
  }
  csum += __shfl_xor(csum, 1);
  csum += __shfl_xor(csum, 2);
  csum += __shfl_xor(csum, 4);
  csum += __shfl_xor(csum, 8);
  csum += __shfl_xor(csum, 16);
  csum += __shfl_xor(csum, 32);
  if (px == 0) vcs[b * DH + ch] = csum;
}

// ---------- attention ----------
// S: bf16 [8 heads][16 rows][224-col pitch, 208 used], rotate-swizzled.
// SROW=448 -> LDS 57856 B -> exactly 2 blocks/CU (L2-friendly regime; R8/R12-verified).
// Softmax: no max-sub (logits ~|6| << 88); exp folded into pass A's register
// epilogue -> the softmax phase is a read-only sum sweep.
#define SROW 448  // bytes per S row
__device__ __forceinline__ int saddr(int g, int i, int j) {
  int r = j * 2 + ((i & 7) << 4);
  if (r >= SROW) r -= SROW;
  return (g * 16 + i) * SROW + r;
}

__global__ __launch_bounds__(512, 4) void k_att(
    const bf16* __restrict__ qf, const bf16* __restrict__ kf,
    const bf16* __restrict__ v4, const bf16* __restrict__ vl,
    const float* __restrict__ vcs,
    const float* __restrict__ ab2g, const float* __restrict__ c1g,
    const float* __restrict__ th2w, const float* __restrict__ th2b,
    bf16* __restrict__ OT) {
  __shared__ __align__(16) char smem[NH * 16 * SROW];  // 57344 B
  __shared__ float smInv[NH * 16];                     // 512 B
  // batch->XCD affinity: all 13 Q-tiles of a batch share one XCD's L2.
  int id = blockIdx.x;            // 1664 linear
  int xcd = id & 7;
  int rest = id >> 3;             // [0,208)
  int qt = rest % 13;
  int b = (rest / 13) * 8 + xcd;  // [0,128), b%8 == xcd
  int i0 = qt * 16;
  int tid = threadIdx.x;
  int wave = tid >> 6, lane = tid & 63;
  int il = lane & 15, kh = lane >> 4;

  // ---- QK^T, head = wave; 16 q-rows x 208 k-rows, raw qk -> S (bf16) ----
  {
    const bf16* qp = qf + ((size_t)b * NH + wave) * QROWS * KD;
    const bf16* kp = kf + ((size_t)b * NH + wave) * QROWS * KD;
    short8 a = *(const short8*)(qp + (i0 + il) * KD + kh * 8);
    for (int jt = 0; jt < 13; ++jt) {
      short8 bb = *(const short8*)(kp + (jt * 16 + il) * KD + kh * 8);
      f32x4 acc = {0.f, 0.f, 0.f, 0.f};
      acc = __builtin_amdgcn_mfma_f32_16x16x32_bf16(a, bb, acc, 0, 0, 0);
      int j = jt * 16 + il;
#pragma unroll
      for (int r = 0; r < 4; ++r)
        *(bf16*)(smem + saddr(wave, kh * 4 + r, j)) = f2b(acc[r]);
    }
  }
  __syncthreads();
  // ---- pass A: th1-mix + bias, writes exp(S') directly (from fp32 registers) ----
  for (int pos = tid; pos < 16 * NPIX; pos += 512) {
    int i = pos / NPIX, j = pos - i * NPIX;
    float sv[8];
#pragma unroll
    for (int h = 0; h < 8; ++h) sv[h] = b2f(*(const bf16*)(smem + saddr(h, i, j)));
    int ia = i0 + i; if (ia > 195) ia = 195;
    int ri = ia / 14, ci = ia - ri * 14;
    int rj = j / 14, cj = j - rj * 14;
    int dr = ri > rj ? ri - rj : rj - ri;
    int dc = ci > cj ? ci - cj : cj - ci;
    int off = dr * 14 + dc;
    float outv[8];
#pragma unroll
    for (int g = 0; g < 8; ++g) {
      float s = ab2g[g * NPIX + off];
#pragma unroll
      for (int h = 0; h < 8; ++h) s += c1g[g * 8 + h] * sv[h];
      outv[g] = s;
    }
#pragma unroll
    for (int g = 0; g < 8; ++g)
      *(bf16*)(smem + saddr(g, i, j)) = f2b(__expf(outv[g]));
  }
  __syncthreads();
  // ---- softmax denom: READ-ONLY sum sweep (exp already in S); 1/sum -> smInv ----
  {
    int row = tid >> 2, part = tid & 3;  // 128 rows = 8 heads x 16
    int g = row >> 4, i = row & 15;
    int jb = part * 52;
    int n4 = (part == 3) ? 10 : 13;  // part 3 covers j in [156,196)
    float s = 0.f;
    for (int it = 0; it < n4; ++it) {
      short4v v = *(const short4v*)(smem + saddr(g, i, jb + it * 4));
#pragma unroll
      for (int t = 0; t < 4; ++t) s += us2f((unsigned short)v[t]);
    }
    if (part == 3) {  // zero pad cols [196,208)
      short4v z = {0, 0, 0, 0};
#pragma unroll
      for (int it = 0; it < 3; ++it)
        *(short4v*)(smem + saddr(g, i, 196 + it * 4)) = z;
    }
    s += __shfl_xor(s, 1);
    s += __shfl_xor(s, 2);
    if (part == 0) smInv[row] = 1.f / s;
  }
  __syncthreads();
  // ---- pass C: talking-head-2 mix with folded 1/sum ----
  for (int pos = tid; pos < 16 * NPIX; pos += 512) {
    int i = pos / NPIX, j = pos - i * NPIX;
    float pv[8];
#pragma unroll
    for (int g = 0; g < 8; ++g)
      pv[g] = b2f(*(const bf16*)(smem + saddr(g, i, j))) * smInv[g * 16 + i];
#pragma unroll
    for (int g2 = 0; g2 < 8; ++g2) {
      float s = 0.f;
#pragma unroll
      for (int g = 0; g < 8; ++g) s += th2w[g2 * 8 + g] * pv[g];
      *(bf16*)(smem + saddr(g2, i, j)) = f2b(s);
    }
  }
  __syncthreads();
  // ---- PV via mfma_f32_32x32x16_bf16, A=P (rows=i), B=V (cols=ch) ----
  // D[m=i (rows 0..15 valid)][n=ch-sub (32 lanes)] -> coalesced 64B OT stores.
  {
    int g = wave;
    int cl = lane & 31, s = lane >> 5;
    const bf16* vb0 = v4 + ((size_t)b * DH + g * DHEAD) * VP;
    float t2b = th2b[g];
#pragma unroll
    for (int dt2 = 0; dt2 < 4; ++dt2) {
      f32x16 acc;
#pragma unroll
      for (int r = 0; r < 16; ++r) acc[r] = 0.f;
      const bf16* vrow = vb0 + (size_t)(dt2 * 32 + cl) * VP + s * 8;
      for (int ks = 0; ks < 13; ++ks) {
        short8 pa = *(const short8*)(smem + saddr(g, cl & 15, ks * 16 + s * 8));
        short8 av = *(const short8*)(vrow + ks * 16);
        acc = __builtin_amdgcn_mfma_f32_32x32x16_bf16(pa, av, acc, 0, 0, 0);
      }
      int ch = g * DHEAD + dt2 * 32 + cl;
      float csv = vcs[b * DH + ch] * t2b;
      const bf16* vlrow = vl + ((size_t)b * DH + ch) * NPIX;
      bf16* otcol = OT + (size_t)b * NPAD * DH + ch;
#pragma unroll
      for (int reg = 0; reg < 8; ++reg) {  // D rows 0..15 only
        int i = (reg & 3) + 8 * (reg >> 2) + 4 * s;
        int n = i0 + i;
        if (n < NPIX) {
          float val = acc[reg] + csv + b2f(vlrow[n]);
          otcol[(size_t)n * DH] = f2b(fmaxf(val, 0.f));
        } else {
          otcol[(size_t)n * DH] = f2b(0.f);
        }
      }
    }
  }
}

extern "C" void kernel_launch(void* const* d_in, const int* in_sizes, int n_in,
                              void* d_out, int out_size, void* d_ws, size_t ws_size,
                              hipStream_t stream) {
  const float* x    = (const float*)d_in[0];
  const float* qw   = (const float*)d_in[1];
  const float* qb   = (const float*)d_in[2];
  const float* q_s  = (const float*)d_in[3];
  const float* q_t  = (const float*)d_in[4];
  const float* kw   = (const float*)d_in[5];
  const float* kb   = (const float*)d_in[6];
  const float* k_s  = (const float*)d_in[7];
  const float* k_t  = (const float*)d_in[8];
  const float* vw   = (const float*)d_in[9];
  const float* vb   = (const float*)d_in[10];
  const float* v_s  = (const float*)d_in[11];
  const float* v_t  = (const float*)d_in[12];
  const float* lvw  = (const float*)d_in[13];
  const float* lvb  = (const float*)d_in[14];
  const float* lv_s = (const float*)d_in[15];
  const float* lv_t = (const float*)d_in[16];
  const float* th1w = (const float*)d_in[17];
  const float* th1b = (const float*)d_in[18];
  const float* th2w = (const float*)d_in[19];
  const float* th2b = (const float*)d_in[20];
  const float* ab   = (const float*)d_in[21];
  const float* pw   = (const float*)d_in[22];
  const float* pb   = (const float*)d_in[23];
  const float* p_s  = (const float*)d_in[24];
  const float* p_t  = (const float*)d_in[25];

  char* ws = (char*)d_ws;
  size_t off = 0;
  auto alloc = [&](size_t bytes) {
    char* p = ws + off;
    off += (bytes + 255) & ~(size_t)255;
    return p;
  };
  // region0: XT (B,208,384 bf16) aliased with OT (B,208,1024 bf16)
  char* region0 = alloc((size_t)NB * NPAD * DH * 2);
  bf16* XT  = (bf16*)region0;
  bf16* OT  = (bf16*)region0;
  bf16* qfb = (bf16*)alloc((size_t)NB * NH * QROWS * KD * 2);
  bf16* kfb = (bf16*)alloc((size_t)NB * NH * QROWS * KD * 2);
  bf16* v4  = (bf16*)alloc((size_t)NB * DH * VP * 2);
  bf16* vlb = (bf16*)alloc((size_t)NB * DH * NPIX * 2);
  float* vcs = (float*)alloc((size_t)NB * DH * 4);
  bf16* wf  = (bf16*)alloc((size_t)1536 * DIM * 2);  // fused Q|K|V weights
  bf16* wpb = (bf16*)alloc((size_t)DIM * DH * 2);    // immediately follows wf
  float* ab2g = (float*)alloc((size_t)NH * NPIX * 4);
  float* c1g  = (float*)alloc((size_t)64 * 4);
  (void)ws_size; (void)in_sizes; (void)n_in; (void)out_size;

  k_cvt4<<<dim3(3841), 256, 0, stream>>>(qw, kw, vw, pw, wf, th1w, th1b, ab,
                                         ab2g, c1g);
  k_xt<<<dim3(12, 7, NB), 256, 0, stream>>>(x, XT);
  k_qkv2<<<dim3(2496), 256, 0, stream>>>(wf, XT, qb, q_s, q_t, kb, k_s, k_t,
                                         vb, v_s, v_t, qfb, kfb, v4);
  k_dwv<<<dim3(NB * 256), 256, 0, stream>>>(v4, lvw, lvb, lv_s, lv_t, vlb, vcs);
  k_att<<<dim3(1664), 512, 0, stream>>>(qfb, kfb, v4, vlb, vcs,
                                        ab2g, c1g, th2w, th2b, OT);
  k_p2<<<dim3(624), 256, 0, stream>>>(wpb, OT, pb, p_s, p_t, (float*)d_out);
}